// Round 5
// baseline (525.011 us; speedup 1.0000x reference)
//
#include <hip/hip_runtime.h>
#include <math.h>

#define T_STEPS 1000
#define BATCH   256
#define IN_DIM  3
#define HID     512
#define OUT_DIM 2
#define BETA    0.8f
#define THRESH  1.0f
#define TAIL    10

typedef float f32x4 __attribute__((ext_vector_type(4)));

// One thread per (b, 4 consecutive h): full T=1000 LIF recurrence.
// NORMAL (write-back) float4 stores: store retires at L2 (~250 cyc), not HBM
// (~1000+ cyc as with nontemporal), so per-wave store throughput is no longer
// the binding limit (R3/R4 post-mortem: nt stores capped at ~2.6 B/cyc/wave).
// Grid: 512 single-wave blocks (2 per CU); no barriers in the t-loop.
__global__ __launch_bounds__(64) void snn_main(const float* __restrict__ x,
                                               const float* __restrict__ W1,
                                               float* __restrict__ spk) {
    __shared__ float xs[T_STEPS * IN_DIM];  // 12 KB: x[:, b, :]
    const int b     = blockIdx.x >> 1;
    const int hbase = (blockIdx.x & 1) << 8;      // 0 or 256
    const int h0    = hbase + (int)threadIdx.x * 4;

    for (int k = threadIdx.x; k < T_STEPS * IN_DIM; k += 64) {
        int t = k / 3, i = k - 3 * t;
        xs[k] = x[t * (BATCH * IN_DIM) + b * IN_DIM + i];
    }
    float w[4][3];
    #pragma unroll
    for (int j = 0; j < 4; ++j)
        #pragma unroll
        for (int i = 0; i < 3; ++i)
            w[j][i] = W1[(h0 + j) * 3 + i];
    __syncthreads();

    float mem[4] = {0.0f, 0.0f, 0.0f, 0.0f};
    f32x4* op = (f32x4*)(spk + (size_t)b * HID + h0);
    #pragma unroll 4
    for (int t = 0; t < T_STEPS; ++t) {
        const float x0 = xs[t * 3 + 0];
        const float x1 = xs[t * 3 + 1];
        const float x2 = xs[t * 3 + 2];
        f32x4 s;
        #pragma unroll
        for (int j = 0; j < 4; ++j) {
            const float cur = fmaf(x0, w[j][0], fmaf(x1, w[j][1], x2 * w[j][2]));
            // snntorch Leaky, reset='zero': reset uses PREVIOUS mem
            const float keep = (mem[j] > THRESH) ? 0.0f : 1.0f;
            mem[j] = fmaf(BETA, mem[j], cur) * keep;
            s[j] = (mem[j] > THRESH) ? 1.0f : 0.0f;
        }
        op[(size_t)t * (BATCH * HID / 4)] = s;   // normal write-back store
    }
}

// avg_out[b][o] = mean over last 10 t of sigmoid( sum_h spk[t,b,h] * W2[o,h] )
// One block per b; 10 waves, one per tail timestep; LDS combine.
__global__ __launch_bounds__(640) void snn_tail(const float* __restrict__ spk,
                                                const float* __restrict__ W2,
                                                float* __restrict__ avg) {
    __shared__ float partial[TAIL][OUT_DIM];
    const int b    = blockIdx.x;
    const int wv   = threadIdx.x >> 6;   // 0..9 = tail index
    const int lane = threadIdx.x & 63;
    const int t    = T_STEPS - TAIL + wv;

    const float* sp = spk + (size_t)t * (BATCH * HID) + b * HID;
    float s0 = 0.0f, s1 = 0.0f;
    #pragma unroll
    for (int j = 0; j < 8; ++j) {
        const int h = lane + j * 64;
        const float v = sp[h];
        s0 = fmaf(v, W2[h], s0);
        s1 = fmaf(v, W2[HID + h], s1);
    }
    #pragma unroll
    for (int off = 32; off > 0; off >>= 1) {
        s0 += __shfl_down(s0, off, 64);
        s1 += __shfl_down(s1, off, 64);
    }
    if (lane == 0) {
        partial[wv][0] = 1.0f / (1.0f + expf(-s0));
        partial[wv][1] = 1.0f / (1.0f + expf(-s1));
    }
    __syncthreads();
    if (threadIdx.x < OUT_DIM) {
        float a = 0.0f;
        #pragma unroll
        for (int i = 0; i < TAIL; ++i) a += partial[i][threadIdx.x];
        avg[b * OUT_DIM + threadIdx.x] = a * (1.0f / TAIL);
    }
}

extern "C" void kernel_launch(void* const* d_in, const int* in_sizes, int n_in,
                              void* d_out, int out_size, void* d_ws, size_t ws_size,
                              hipStream_t stream) {
    const float* x  = (const float*)d_in[0];   // [1000,256,3]
    const float* W1 = (const float*)d_in[1];   // [512,3]
    const float* W2 = (const float*)d_in[2];   // [2,512]
    float* out = (float*)d_out;
    float* spk = out;                                        // [1000,256,512]
    float* avg = out + (size_t)T_STEPS * BATCH * HID;        // [256,2]

    snn_main<<<dim3(BATCH * 2), dim3(64), 0, stream>>>(x, W1, spk);
    snn_tail<<<dim3(BATCH), dim3(640), 0, stream>>>(spk, W2, avg);
}

// Round 6
// 524.746 us; speedup vs baseline: 1.0005x; 1.0005x over previous
//
#include <hip/hip_runtime.h>
#include <math.h>

#define T_STEPS 1000
#define BATCH   256
#define IN_DIM  3
#define HID     512
#define OUT_DIM 2
#define BETA    0.8f
#define THRESH  1.0f
#define TAIL    10
#define TCHUNK  8

typedef float f32x4 __attribute__((ext_vector_type(4)));

// One thread per (b, 4 consecutive h). The T=1000 recurrence is computed in
// register-buffered chunks of 8 timesteps; then 8 x 1KB wave-stores issue
// BACK-TO-BACK. R1-R5 post-mortem: effective write BW was pinned at ~3.2 TB/s
// in every variant because one store per ~70-cyc t-iteration keeps only ~3.5
// stores/wave in flight (Little's law needs ~7 at HBM ack latency). Bursting
// 8 stores doubles bytes-in-flight without changing anything else.
__global__ __launch_bounds__(64) void snn_main(const float* __restrict__ x,
                                               const float* __restrict__ W1,
                                               float* __restrict__ spk) {
    __shared__ float xs[T_STEPS * IN_DIM];  // 12 KB: x[:, b, :]
    const int b     = blockIdx.x >> 1;
    const int hbase = (blockIdx.x & 1) << 8;      // 0 or 256
    const int h0    = hbase + (int)threadIdx.x * 4;

    for (int k = threadIdx.x; k < T_STEPS * IN_DIM; k += 64) {
        int t = k / 3, i = k - 3 * t;
        xs[k] = x[t * (BATCH * IN_DIM) + b * IN_DIM + i];
    }
    float w[4][3];
    #pragma unroll
    for (int j = 0; j < 4; ++j)
        #pragma unroll
        for (int i = 0; i < 3; ++i)
            w[j][i] = W1[(h0 + j) * 3 + i];
    __syncthreads();

    float mem[4] = {0.0f, 0.0f, 0.0f, 0.0f};
    f32x4* op = (f32x4*)(spk + (size_t)b * HID + h0);
    f32x4 sbuf[TCHUNK];

    for (int t0 = 0; t0 < T_STEPS; t0 += TCHUNK) {
        // Phase 1: compute 8 timesteps into registers (no stores).
        #pragma unroll
        for (int u = 0; u < TCHUNK; ++u) {
            const int t = t0 + u;
            const float x0 = xs[t * 3 + 0];
            const float x1 = xs[t * 3 + 1];
            const float x2 = xs[t * 3 + 2];
            f32x4 s;
            #pragma unroll
            for (int j = 0; j < 4; ++j) {
                const float cur = fmaf(x0, w[j][0], fmaf(x1, w[j][1], x2 * w[j][2]));
                // snntorch Leaky, reset='zero': reset uses PREVIOUS mem
                const float keep = (mem[j] > THRESH) ? 0.0f : 1.0f;
                mem[j] = fmaf(BETA, mem[j], cur) * keep;
                s[j] = (mem[j] > THRESH) ? 1.0f : 0.0f;
            }
            sbuf[u] = s;
        }
        // Phase 2: 8 back-to-back 1KB wave stores (deep store pipeline).
        #pragma unroll
        for (int u = 0; u < TCHUNK; ++u)
            op[(size_t)(t0 + u) * (BATCH * HID / 4)] = sbuf[u];
    }
}

// avg_out[b][o] = mean over last 10 t of sigmoid( sum_h spk[t,b,h] * W2[o,h] )
// One block per b; 10 waves, one per tail timestep; LDS combine.
__global__ __launch_bounds__(640) void snn_tail(const float* __restrict__ spk,
                                                const float* __restrict__ W2,
                                                float* __restrict__ avg) {
    __shared__ float partial[TAIL][OUT_DIM];
    const int b    = blockIdx.x;
    const int wv   = threadIdx.x >> 6;   // 0..9 = tail index
    const int lane = threadIdx.x & 63;
    const int t    = T_STEPS - TAIL + wv;

    const float* sp = spk + (size_t)t * (BATCH * HID) + b * HID;
    float s0 = 0.0f, s1 = 0.0f;
    #pragma unroll
    for (int j = 0; j < 8; ++j) {
        const int h = lane + j * 64;
        const float v = sp[h];
        s0 = fmaf(v, W2[h], s0);
        s1 = fmaf(v, W2[HID + h], s1);
    }
    #pragma unroll
    for (int off = 32; off > 0; off >>= 1) {
        s0 += __shfl_down(s0, off, 64);
        s1 += __shfl_down(s1, off, 64);
    }
    if (lane == 0) {
        partial[wv][0] = 1.0f / (1.0f + expf(-s0));
        partial[wv][1] = 1.0f / (1.0f + expf(-s1));
    }
    __syncthreads();
    if (threadIdx.x < OUT_DIM) {
        float a = 0.0f;
        #pragma unroll
        for (int i = 0; i < TAIL; ++i) a += partial[i][threadIdx.x];
        avg[b * OUT_DIM + threadIdx.x] = a * (1.0f / TAIL);
    }
}

extern "C" void kernel_launch(void* const* d_in, const int* in_sizes, int n_in,
                              void* d_out, int out_size, void* d_ws, size_t ws_size,
                              hipStream_t stream) {
    const float* x  = (const float*)d_in[0];   // [1000,256,3]
    const float* W1 = (const float*)d_in[1];   // [512,3]
    const float* W2 = (const float*)d_in[2];   // [2,512]
    float* out = (float*)d_out;
    float* spk = out;                                        // [1000,256,512]
    float* avg = out + (size_t)T_STEPS * BATCH * HID;        // [256,2]

    snn_main<<<dim3(BATCH * 2), dim3(64), 0, stream>>>(x, W1, spk);
    snn_tail<<<dim3(BATCH), dim3(640), 0, stream>>>(spk, W2, avg);
}